// Round 5
// baseline (348.093 us; speedup 1.0000x reference)
//
#include <hip/hip_runtime.h>

// TextCNN: B=128, S=512, E=300, H=64, k_i = i/2+2 in [2,33].
// Virtual-im2col bf16 MFMA GEMM, fused gather, 4-chunk E-split LDS staging.
//   Grid: 128 b x 11 t-slices (48 rows each) = 1408 blocks -> ALL co-resident
//   (5-6 blocks/CU), single dispatch wave.
//   Block: 256 thr = 4 waves = 4-way j(K)-split (jq). Each wave owns all
//   3 M-tiles x its balanced j-quarter (21 (j,g)-units -> 315 MFMA/chunk-triple).
//   E chunks: {96,96,96,12pad32} elems -> LP=104, At = 80 rows x 208 B = 16.6 KB
//   (R3's 42 KB capped residency at 3 blocks/CU; R3 counters showed no pipe
//   >37% busy -> latency-bound, needs more waves, not fewer reads).
//   acc[3][4] = 48 VGPRs; launch_bounds(256,5) caps at 102 -- 18-reg cushion
//   over the ~84 natural demand (R1/R2/R4 all spilled when cap ~= demand).
//   Epilogue: 4-phase jq tree-reduce in LDS (no atomics), tanh + masked max.
// ws layout: [0, 860160) wsB bf16 | [860160, +360448) wsF f32 (128*64*11).

#define SS     512
#define EE     300
#define HH     64
#define KMAXW  33
#define LP     104          // LDS row pitch in elems (208 B); 52 dw == 20 mod 32
#define RP     68           // epilogue reduce pitch (floats)

typedef __attribute__((ext_vector_type(8))) short bf16x8;
typedef __attribute__((ext_vector_type(4))) float f32x4;

__device__ __forceinline__ unsigned short f2bf(float f) {
    unsigned u = __float_as_uint(f);
    unsigned r = ((u >> 16) & 1u) + 0x7FFFu;   // round-to-nearest-even
    return (unsigned short)((u + r) >> 16);
}

// ---- Kernel 1: repack Wconv (f32 [64][33][300]) -> wsB bf16, fragment order.
// Layout: [chunk c][group g][j*uc+u][512], uc = {3,3,3,1}, chunk base = c*129024.
// Group step-bases within chunk: CUMJ[g]*uc, CUMJ = {0,9,26,51} (Jg = 8g+9).
__global__ __launch_bounds__(256) void prep_weights(const float* __restrict__ Wconv,
                                                    unsigned short* __restrict__ wsB) {
    int idx = blockIdx.x * 256 + threadIdx.x;      // < 430080
    int r    = idx & 7;
    int lane = (idx >> 3) & 63;
    int gs   = idx >> 9;                           // < 840 steps
    int c, w2, uc;
    if (gs < 756) { c = gs / 252; w2 = gs - c * 252; uc = 3; }
    else          { c = 3;        w2 = gs - 756;     uc = 1; }
    int g, t;
    if (uc == 3) {
        if      (w2 < 27)  { g = 0; t = w2;       }
        else if (w2 < 78)  { g = 1; t = w2 - 27;  }
        else if (w2 < 153) { g = 2; t = w2 - 78;  }
        else               { g = 3; t = w2 - 153; }
    } else {
        if      (w2 < 9)   { g = 0; t = w2;       }
        else if (w2 < 26)  { g = 1; t = w2 - 9;   }
        else if (w2 < 51)  { g = 2; t = w2 - 26;  }
        else               { g = 3; t = w2 - 51;  }
    }
    int j = t / uc, u = t - j * uc;
    int i  = g * 16 + (lane & 15);
    int ki = i / 2 + 2;
    int kk = (lane >> 4) * 8 + r;
    int e  = c * 96 + u * 32 + kk;
    float v = 0.f;
    if (e < EE && j < ki) v = Wconv[(i * KMAXW + j) * EE + e];
    wsB[idx] = f2bf(v);
}

#define MFMA(A, Bf, C) __builtin_amdgcn_mfma_f32_16x16x32_bf16((A), (Bf), (C), 0, 0, 0)

// One j-segment of one chunk: groups g in [G0,4) active (G-pure j range).
// ar0 = At + m*LP + q*8; bp = wsB + c*129024 + lane*8.
// B loaded first (<= 4 frags live), then one a-frag streams through its MFMAs.
template<int G0, int UC>
__device__ __forceinline__ void seg(const unsigned short* __restrict__ ar0,
                                    int jlo, int jhi,
                                    const unsigned short* __restrict__ bp,
                                    f32x4 acc[3][4]) {
    constexpr int CUMJ[4] = {0, 9, 26, 51};
    #pragma unroll 1
    for (int j = jlo; j < jhi; ++j) {
        const unsigned short* ar = ar0 + j * LP;
        #pragma unroll
        for (int u = 0; u < UC; ++u) {
            bf16x8 bf[4];
            #pragma unroll
            for (int g = G0; g < 4; ++g)
                bf[g] = *(const bf16x8*)(bp + ((CUMJ[g] + j) * UC + u) * 512);
            #pragma unroll
            for (int t = 0; t < 3; ++t) {
                bf16x8 a = *(const bf16x8*)(ar + t * (16 * LP) + u * 32);
                #pragma unroll
                for (int g = G0; g < 4; ++g)
                    acc[t][g] = MFMA(a, bf[g], acc[t][g]);
            }
        }
    }
}

// ---- Kernel 2: fused gather + GEMM + cross-wave reduce + tanh + masked max.
__global__ __launch_bounds__(256, 5) void conv_fused(const int* __restrict__ x,
                                                     const float* __restrict__ emb,
                                                     const unsigned short* __restrict__ wsB,
                                                     const float* __restrict__ bconv,
                                                     float* __restrict__ wsF) {
    __shared__ __align__(16) unsigned short At[80 * LP];   // 16640 B

    int b     = blockIdx.x / 11;
    int slice = blockIdx.x - b * 11;
    int t0    = slice * 48;

    int lane = threadIdx.x & 63;
    int jq   = threadIdx.x >> 6;       // wave id = j-quarter (SIMD-balanced)
    int m = lane & 15, q = lane >> 4;

    f32x4 acc[3][4] = {};

    const unsigned short* ar0 = At + m * LP + q * 8;

    #pragma unroll 1
    for (int c = 0; c < 4; ++c) {
        if (c) __syncthreads();        // all reads of previous chunk complete

        // Stage 80 rows (48 + 32 halo) of chunk c, f32 -> bf16, zero-padded.
        if (c < 3) {                   // 96 elems/row = 12 bf16x8
            #pragma unroll
            for (int it = 0; it < 4; ++it) {
                int idx = threadIdx.x + it * 256;          // < 960
                if (idx < 960) {
                    int rr = idx / 12, cc = idx - rr * 12;
                    int srow = t0 + rr;
                    bf16x8 v = {0, 0, 0, 0, 0, 0, 0, 0};
                    if (srow < SS) {
                        int tok = x[b * SS + srow];
                        const float* ep = emb + (long)tok * EE + c * 96 + cc * 8;
                        float4 f0 = ((const float4*)ep)[0];
                        float4 f1 = ((const float4*)ep)[1];
                        v[0] = f2bf(f0.x); v[1] = f2bf(f0.y); v[2] = f2bf(f0.z); v[3] = f2bf(f0.w);
                        v[4] = f2bf(f1.x); v[5] = f2bf(f1.y); v[6] = f2bf(f1.z); v[7] = f2bf(f1.w);
                    }
                    *(bf16x8*)&At[rr * LP + cc * 8] = v;
                }
            }
        } else {                       // elems 288..299 valid, pad to 32
            #pragma unroll
            for (int it = 0; it < 2; ++it) {
                int idx = threadIdx.x + it * 256;          // < 320
                if (idx < 320) {
                    int rr = idx >> 2, cc = idx & 3;
                    int srow = t0 + rr;
                    bf16x8 v = {0, 0, 0, 0, 0, 0, 0, 0};
                    if (srow < SS && cc < 2) {
                        int tok = x[b * SS + srow];
                        const float* ep = emb + (long)tok * EE + 288 + cc * 8;
                        float4 f0 = ((const float4*)ep)[0];
                        v[0] = f2bf(f0.x); v[1] = f2bf(f0.y); v[2] = f2bf(f0.z); v[3] = f2bf(f0.w);
                        if (cc == 0) {                     // 288..295 all valid
                            float4 f1 = ((const float4*)ep)[1];
                            v[4] = f2bf(f1.x); v[5] = f2bf(f1.y); v[6] = f2bf(f1.z); v[7] = f2bf(f1.w);
                        }                                  // cc==1: 296..299 only
                    }
                    *(bf16x8*)&At[rr * LP + cc * 8] = v;
                }
            }
        }
        __syncthreads();

        const unsigned short* bp = wsB + c * 129024 + lane * 8;
        // j-regions by active-group count: [0,9):4g, [9,17):3g, [17,25):2g, [25,33):1g.
        // 4-way split, 21 (j,g)-units per wave (exact SIMD balance):
        //   jq0: [0,3)+[9,12); jq1: [3,6)+[12,15); jq2: [6,9)+[15,17)+[25,28);
        //   jq3: [17,25)+[28,33).
        if (c < 3) {
            if      (jq == 0) { seg<0,3>(ar0, 0, 3,  bp, acc); seg<1,3>(ar0, 9, 12,  bp, acc); }
            else if (jq == 1) { seg<0,3>(ar0, 3, 6,  bp, acc); seg<1,3>(ar0, 12, 15, bp, acc); }
            else if (jq == 2) { seg<0,3>(ar0, 6, 9,  bp, acc); seg<1,3>(ar0, 15, 17, bp, acc);
                                seg<3,3>(ar0, 25, 28, bp, acc); }
            else              { seg<2,3>(ar0, 17, 25, bp, acc); seg<3,3>(ar0, 28, 33, bp, acc); }
        } else {
            if      (jq == 0) { seg<0,1>(ar0, 0, 3,  bp, acc); seg<1,1>(ar0, 9, 12,  bp, acc); }
            else if (jq == 1) { seg<0,1>(ar0, 3, 6,  bp, acc); seg<1,1>(ar0, 12, 15, bp, acc); }
            else if (jq == 2) { seg<0,1>(ar0, 6, 9,  bp, acc); seg<1,1>(ar0, 15, 17, bp, acc);
                                seg<3,1>(ar0, 25, 28, bp, acc); }
            else              { seg<2,1>(ar0, 17, 25, bp, acc); seg<3,1>(ar0, 28, 33, bp, acc); }
        }
    }

    // ---- Epilogue: 4-phase jq tree-reduce in LDS, then tanh + masked max.
    __syncthreads();                                  // done reading At
    float* red  = (float*)At;                         // [48][RP] = 13056 B
    float* red2 = red + 48 * RP;                      // [4][64]  = 1024 B (total 14080 <= 16640)

    // C/D map: col = m (filter in group), row = t*16 + q*4 + r.
    #pragma unroll
    for (int ph = 0; ph < 4; ++ph) {
        if (jq == ph) {
            #pragma unroll
            for (int t = 0; t < 3; ++t)
                #pragma unroll
                for (int g = 0; g < 4; ++g)
                    #pragma unroll
                    for (int r = 0; r < 4; ++r) {
                        float* dst = &red[(t * 16 + q * 4 + r) * RP + g * 16 + m];
                        if (ph == 0) *dst = acc[t][g][r];
                        else         *dst += acc[t][g][r];
                    }
        }
        __syncthreads();
    }

    int f  = threadIdx.x & 63;                        // filter
    int rg = threadIdx.x >> 6;                        // row group (12 rows each)
    int ki = (f >> 1) + 2;
    int tmax = SS - ki;
    float bc = bconv[f];
    float mx = -3.0e38f;
    #pragma unroll 1
    for (int rr = 0; rr < 12; ++rr) {
        int row = rg * 12 + rr;
        int tb  = t0 + row;
        float v = tanhf(red[row * RP + f] + bc);
        if (tb <= tmax) mx = fmaxf(mx, v);
    }
    red2[rg * 64 + f] = mx;
    __syncthreads();
    if (threadIdx.x < 64) {
        float v = fmaxf(fmaxf(red2[f], red2[64 + f]),
                        fmaxf(red2[128 + f], red2[192 + f]));
        wsF[(b * HH + f) * 11 + slice] = v;
    }
}

// ---- Kernel 3: max over 11 partials, linear, sigmoid. 128 blocks x 64 thr.
__global__ __launch_bounds__(64) void final_linear(const float* __restrict__ wsF,
                                                   const float* __restrict__ Wlin,
                                                   const float* __restrict__ blin,
                                                   float* __restrict__ out) {
    int b = blockIdx.x;
    int i = threadIdx.x;
    const float* pp = wsF + (b * HH + i) * 11;
    float mx = pp[0];
    #pragma unroll
    for (int j = 1; j < 11; ++j) mx = fmaxf(mx, pp[j]);
    float v = mx * Wlin[i];
    #pragma unroll
    for (int off = 1; off < 64; off <<= 1) v += __shfl_xor(v, off);
    if (i == 0) out[b] = 1.0f / (1.0f + expf(-(v + blin[0])));
}

extern "C" void kernel_launch(void* const* d_in, const int* in_sizes, int n_in,
                              void* d_out, int out_size, void* d_ws, size_t ws_size,
                              hipStream_t stream) {
    const int*   x     = (const int*)d_in[0];
    const float* emb   = (const float*)d_in[1];
    const float* Wconv = (const float*)d_in[2];
    const float* bconv = (const float*)d_in[3];
    const float* Wlin  = (const float*)d_in[4];
    const float* blin  = (const float*)d_in[5];
    float* out = (float*)d_out;

    unsigned short* wsB = (unsigned short*)d_ws;
    float*          wsF = (float*)((char*)d_ws + 860160);   // wsB = 430080*2 B

    prep_weights<<<1680, 256, 0, stream>>>(Wconv, wsB);
    conv_fused<<<1408, 256, 0, stream>>>(x, emb, wsB, bconv, wsF);
    final_linear<<<128, 64, 0, stream>>>(wsF, Wlin, blin, out);
}

// Round 6
// 211.192 us; speedup vs baseline: 1.6482x; 1.6482x over previous
//
#include <hip/hip_runtime.h>

// TextCNN: B=128, S=512, E=300, H=64, k_i = i/2+2 in [2,33].
// Virtual-im2col bf16 MFMA GEMM, fused gather, 4-chunk E-split LDS staging.
//   Grid: 128 b x 11 t-slices (48 rows each) = 1408 blocks.
//   Block: 256 thr = 4 waves = 4-way j(K)-split (jq). Each wave owns all
//   3 M-tiles x its balanced j-quarter (21 (j,g)-units -> 315 MFMA/chunk-triple).
//   E chunks: {96,96,96,12pad32} elems -> LP=104, At = 80 rows x 208 B = 16.6 KB.
//   REGISTER RULE (R1/R2/R4/R5 post-mortems): unified VGPR+AGPR demand of this
//   inner loop ~130-170; launch_bounds cap must be >= that or the allocator
//   spills acc to scratch (R5: cap 102 -> VGPR 48 + 330MB scratch writes).
//   (256,3) -> cap ~170: proven spill-free (R3). Runtime occupancy then comes
//   from ACTUAL use: min(LDS 160/16.6=9, VGPR 512/84=6 waves/SIMD, 8 blk thr)
//   = 6 blocks/CU = 75% -- the latency-hiding R3's counters called for.
//   Epilogue: 4-phase jq tree-reduce in LDS (no atomics), tanh + masked max.
// ws layout: [0, 860160) wsB bf16 | [860160, +360448) wsF f32 (128*64*11).

#define SS     512
#define EE     300
#define HH     64
#define KMAXW  33
#define LP     104          // LDS row pitch in elems (208 B); 52 dw == 20 mod 32
#define RP     68           // epilogue reduce pitch (floats)

typedef __attribute__((ext_vector_type(8))) short bf16x8;
typedef __attribute__((ext_vector_type(4))) float f32x4;

__device__ __forceinline__ unsigned short f2bf(float f) {
    unsigned u = __float_as_uint(f);
    unsigned r = ((u >> 16) & 1u) + 0x7FFFu;   // round-to-nearest-even
    return (unsigned short)((u + r) >> 16);
}

// ---- Kernel 1: repack Wconv (f32 [64][33][300]) -> wsB bf16, fragment order.
// Layout: [chunk c][group g][j*uc+u][512], uc = {3,3,3,1}, chunk base = c*129024.
// Group step-bases within chunk: CUMJ[g]*uc, CUMJ = {0,9,26,51} (Jg = 8g+9).
__global__ __launch_bounds__(256) void prep_weights(const float* __restrict__ Wconv,
                                                    unsigned short* __restrict__ wsB) {
    int idx = blockIdx.x * 256 + threadIdx.x;      // < 430080
    int r    = idx & 7;
    int lane = (idx >> 3) & 63;
    int gs   = idx >> 9;                           // < 840 steps
    int c, w2, uc;
    if (gs < 756) { c = gs / 252; w2 = gs - c * 252; uc = 3; }
    else          { c = 3;        w2 = gs - 756;     uc = 1; }
    int g, t;
    if (uc == 3) {
        if      (w2 < 27)  { g = 0; t = w2;       }
        else if (w2 < 78)  { g = 1; t = w2 - 27;  }
        else if (w2 < 153) { g = 2; t = w2 - 78;  }
        else               { g = 3; t = w2 - 153; }
    } else {
        if      (w2 < 9)   { g = 0; t = w2;       }
        else if (w2 < 26)  { g = 1; t = w2 - 9;   }
        else if (w2 < 51)  { g = 2; t = w2 - 26;  }
        else               { g = 3; t = w2 - 51;  }
    }
    int j = t / uc, u = t - j * uc;
    int i  = g * 16 + (lane & 15);
    int ki = i / 2 + 2;
    int kk = (lane >> 4) * 8 + r;
    int e  = c * 96 + u * 32 + kk;
    float v = 0.f;
    if (e < EE && j < ki) v = Wconv[(i * KMAXW + j) * EE + e];
    wsB[idx] = f2bf(v);
}

#define MFMA(A, Bf, C) __builtin_amdgcn_mfma_f32_16x16x32_bf16((A), (Bf), (C), 0, 0, 0)

// One j-segment of one chunk: groups g in [G0,4) active (G-pure j range).
// ar0 = At + m*LP + q*8; bp = wsB + c*129024 + lane*8.
// B loaded first (<= 4 frags live), then one a-frag streams through its MFMAs.
template<int G0, int UC>
__device__ __forceinline__ void seg(const unsigned short* __restrict__ ar0,
                                    int jlo, int jhi,
                                    const unsigned short* __restrict__ bp,
                                    f32x4 acc[3][4]) {
    constexpr int CUMJ[4] = {0, 9, 26, 51};
    #pragma unroll 1
    for (int j = jlo; j < jhi; ++j) {
        const unsigned short* ar = ar0 + j * LP;
        #pragma unroll
        for (int u = 0; u < UC; ++u) {
            bf16x8 bf[4];
            #pragma unroll
            for (int g = G0; g < 4; ++g)
                bf[g] = *(const bf16x8*)(bp + ((CUMJ[g] + j) * UC + u) * 512);
            #pragma unroll
            for (int t = 0; t < 3; ++t) {
                bf16x8 a = *(const bf16x8*)(ar + t * (16 * LP) + u * 32);
                #pragma unroll
                for (int g = G0; g < 4; ++g)
                    acc[t][g] = MFMA(a, bf[g], acc[t][g]);
            }
        }
    }
}

// ---- Kernel 2: fused gather + GEMM + cross-wave reduce + tanh + masked max.
__global__ __launch_bounds__(256, 3) void conv_fused(const int* __restrict__ x,
                                                     const float* __restrict__ emb,
                                                     const unsigned short* __restrict__ wsB,
                                                     const float* __restrict__ bconv,
                                                     float* __restrict__ wsF) {
    __shared__ __align__(16) unsigned short At[80 * LP];   // 16640 B

    int b     = blockIdx.x / 11;
    int slice = blockIdx.x - b * 11;
    int t0    = slice * 48;

    int lane = threadIdx.x & 63;
    int jq   = threadIdx.x >> 6;       // wave id = j-quarter (SIMD-balanced)
    int m = lane & 15, q = lane >> 4;

    f32x4 acc[3][4] = {};

    const unsigned short* ar0 = At + m * LP + q * 8;

    #pragma unroll 1
    for (int c = 0; c < 4; ++c) {
        if (c) __syncthreads();        // all reads of previous chunk complete

        // Stage 80 rows (48 + 32 halo) of chunk c, f32 -> bf16, zero-padded.
        if (c < 3) {                   // 96 elems/row = 12 bf16x8
            #pragma unroll
            for (int it = 0; it < 4; ++it) {
                int idx = threadIdx.x + it * 256;          // < 960
                if (idx < 960) {
                    int rr = idx / 12, cc = idx - rr * 12;
                    int srow = t0 + rr;
                    bf16x8 v = {0, 0, 0, 0, 0, 0, 0, 0};
                    if (srow < SS) {
                        int tok = x[b * SS + srow];
                        const float* ep = emb + (long)tok * EE + c * 96 + cc * 8;
                        float4 f0 = ((const float4*)ep)[0];
                        float4 f1 = ((const float4*)ep)[1];
                        v[0] = f2bf(f0.x); v[1] = f2bf(f0.y); v[2] = f2bf(f0.z); v[3] = f2bf(f0.w);
                        v[4] = f2bf(f1.x); v[5] = f2bf(f1.y); v[6] = f2bf(f1.z); v[7] = f2bf(f1.w);
                    }
                    *(bf16x8*)&At[rr * LP + cc * 8] = v;
                }
            }
        } else {                       // elems 288..299 valid, pad to 32
            #pragma unroll
            for (int it = 0; it < 2; ++it) {
                int idx = threadIdx.x + it * 256;          // < 320
                if (idx < 320) {
                    int rr = idx >> 2, cc = idx & 3;
                    int srow = t0 + rr;
                    bf16x8 v = {0, 0, 0, 0, 0, 0, 0, 0};
                    if (srow < SS && cc < 2) {
                        int tok = x[b * SS + srow];
                        const float* ep = emb + (long)tok * EE + 288 + cc * 8;
                        float4 f0 = ((const float4*)ep)[0];
                        v[0] = f2bf(f0.x); v[1] = f2bf(f0.y); v[2] = f2bf(f0.z); v[3] = f2bf(f0.w);
                        if (cc == 0) {                     // 288..295 all valid
                            float4 f1 = ((const float4*)ep)[1];
                            v[4] = f2bf(f1.x); v[5] = f2bf(f1.y); v[6] = f2bf(f1.z); v[7] = f2bf(f1.w);
                        }                                  // cc==1: 296..299 only
                    }
                    *(bf16x8*)&At[rr * LP + cc * 8] = v;
                }
            }
        }
        __syncthreads();

        const unsigned short* bp = wsB + c * 129024 + lane * 8;
        // j-regions by active-group count: [0,9):4g, [9,17):3g, [17,25):2g, [25,33):1g.
        // 4-way split, 21 (j,g)-units per wave (exact SIMD balance):
        //   jq0: [0,3)+[9,12); jq1: [3,6)+[12,15); jq2: [6,9)+[15,17)+[25,28);
        //   jq3: [17,25)+[28,33).
        if (c < 3) {
            if      (jq == 0) { seg<0,3>(ar0, 0, 3,  bp, acc); seg<1,3>(ar0, 9, 12,  bp, acc); }
            else if (jq == 1) { seg<0,3>(ar0, 3, 6,  bp, acc); seg<1,3>(ar0, 12, 15, bp, acc); }
            else if (jq == 2) { seg<0,3>(ar0, 6, 9,  bp, acc); seg<1,3>(ar0, 15, 17, bp, acc);
                                seg<3,3>(ar0, 25, 28, bp, acc); }
            else              { seg<2,3>(ar0, 17, 25, bp, acc); seg<3,3>(ar0, 28, 33, bp, acc); }
        } else {
            if      (jq == 0) { seg<0,1>(ar0, 0, 3,  bp, acc); seg<1,1>(ar0, 9, 12,  bp, acc); }
            else if (jq == 1) { seg<0,1>(ar0, 3, 6,  bp, acc); seg<1,1>(ar0, 12, 15, bp, acc); }
            else if (jq == 2) { seg<0,1>(ar0, 6, 9,  bp, acc); seg<1,1>(ar0, 15, 17, bp, acc);
                                seg<3,1>(ar0, 25, 28, bp, acc); }
            else              { seg<2,1>(ar0, 17, 25, bp, acc); seg<3,1>(ar0, 28, 33, bp, acc); }
        }
    }

    // ---- Epilogue: 4-phase jq tree-reduce in LDS, then tanh + masked max.
    __syncthreads();                                  // done reading At
    float* red  = (float*)At;                         // [48][RP] = 13056 B
    float* red2 = red + 48 * RP;                      // [4][64]  = 1024 B (total 14080 <= 16640)

    // C/D map: col = m (filter in group), row = t*16 + q*4 + r.
    #pragma unroll
    for (int ph = 0; ph < 4; ++ph) {
        if (jq == ph) {
            #pragma unroll
            for (int t = 0; t < 3; ++t)
                #pragma unroll
                for (int g = 0; g < 4; ++g)
                    #pragma unroll
                    for (int r = 0; r < 4; ++r) {
                        float* dst = &red[(t * 16 + q * 4 + r) * RP + g * 16 + m];
                        if (ph == 0) *dst = acc[t][g][r];
                        else         *dst += acc[t][g][r];
                    }
        }
        __syncthreads();
    }

    int f  = threadIdx.x & 63;                        // filter
    int rg = threadIdx.x >> 6;                        // row group (12 rows each)
    int ki = (f >> 1) + 2;
    int tmax = SS - ki;
    float bc = bconv[f];
    float mx = -3.0e38f;
    #pragma unroll 1
    for (int rr = 0; rr < 12; ++rr) {
        int row = rg * 12 + rr;
        int tb  = t0 + row;
        float v = tanhf(red[row * RP + f] + bc);
        if (tb <= tmax) mx = fmaxf(mx, v);
    }
    red2[rg * 64 + f] = mx;
    __syncthreads();
    if (threadIdx.x < 64) {
        float v = fmaxf(fmaxf(red2[f], red2[64 + f]),
                        fmaxf(red2[128 + f], red2[192 + f]));
        wsF[(b * HH + f) * 11 + slice] = v;
    }
}

// ---- Kernel 3: max over 11 partials, linear, sigmoid. 128 blocks x 64 thr.
__global__ __launch_bounds__(64) void final_linear(const float* __restrict__ wsF,
                                                   const float* __restrict__ Wlin,
                                                   const float* __restrict__ blin,
                                                   float* __restrict__ out) {
    int b = blockIdx.x;
    int i = threadIdx.x;
    const float* pp = wsF + (b * HH + i) * 11;
    float mx = pp[0];
    #pragma unroll
    for (int j = 1; j < 11; ++j) mx = fmaxf(mx, pp[j]);
    float v = mx * Wlin[i];
    #pragma unroll
    for (int off = 1; off < 64; off <<= 1) v += __shfl_xor(v, off);
    if (i == 0) out[b] = 1.0f / (1.0f + expf(-(v + blin[0])));
}

extern "C" void kernel_launch(void* const* d_in, const int* in_sizes, int n_in,
                              void* d_out, int out_size, void* d_ws, size_t ws_size,
                              hipStream_t stream) {
    const int*   x     = (const int*)d_in[0];
    const float* emb   = (const float*)d_in[1];
    const float* Wconv = (const float*)d_in[2];
    const float* bconv = (const float*)d_in[3];
    const float* Wlin  = (const float*)d_in[4];
    const float* blin  = (const float*)d_in[5];
    float* out = (float*)d_out;

    unsigned short* wsB = (unsigned short*)d_ws;
    float*          wsF = (float*)((char*)d_ws + 860160);   // wsB = 430080*2 B

    prep_weights<<<1680, 256, 0, stream>>>(Wconv, wsB);
    conv_fused<<<1408, 256, 0, stream>>>(x, emb, wsB, bconv, wsF);
    final_linear<<<128, 64, 0, stream>>>(wsF, Wlin, blin, out);
}